// Round 3
// baseline (110.785 us; speedup 1.0000x reference)
//
#include <hip/hip_runtime.h>

// out[b] = sum_h (x @ W^T)[b,h] * 1.0  ==  dot(x[b,:], colsum_h(W))
// Phase 1: partial column sums of W (512 blocks).
// Phase 2: reduce 128 partials -> wsum.
// Phase 3: matvec, wsum REGISTER-resident per lane (no LDS, no barrier),
//          4 contiguous rows per wave, pure x stream.

#define BATCH   32768
#define HIDDEN  4096
#define INDIM   4096
#define ROWCHUNKS 128
#define ROWS_PER_CHUNK (HIDDEN / ROWCHUNKS)   // 32

typedef float f32x4 __attribute__((ext_vector_type(4)));

// ---------------------------------------------------------------------------
// Kernel 1: partial column sums. grid (4, 128), block 256 -> 512 blocks (2/CU).
__global__ void __launch_bounds__(256)
colsum_partial_kernel(const float* __restrict__ W, float* __restrict__ partial) {
    const int col4 = blockIdx.x * 256 + threadIdx.x;      // 0..1023
    const int row0 = blockIdx.y * ROWS_PER_CHUNK;
    const f32x4* Wv = reinterpret_cast<const f32x4*>(W);
    f32x4 acc = {0.f, 0.f, 0.f, 0.f};
#pragma unroll 16
    for (int r = 0; r < ROWS_PER_CHUNK; ++r) {
        f32x4 v = __builtin_nontemporal_load(&Wv[(size_t)(row0 + r) * (INDIM / 4) + col4]);
        acc += v;
    }
    reinterpret_cast<f32x4*>(partial)[(size_t)blockIdx.y * (INDIM / 4) + col4] = acc;
}

// ---------------------------------------------------------------------------
// Kernel 2: reduce ROWCHUNKS partials -> wsum. One thread per column.
// grid 16, block 256; lanes read consecutive addresses at each step.
__global__ void __launch_bounds__(256)
colsum_final_kernel(const float* __restrict__ partial, float* __restrict__ wsum) {
    const int col = blockIdx.x * 256 + threadIdx.x;       // 0..4095
    float acc = 0.f;
#pragma unroll 8
    for (int p = 0; p < ROWCHUNKS; ++p)
        acc += partial[(size_t)p * INDIM + col];
    wsum[col] = acc;
}

// ---------------------------------------------------------------------------
// Kernel 3: out[b] = dot(x[b,:], wsum). 2048 blocks x 256 threads = 8192 waves,
// 4 contiguous rows per wave. Lane l keeps w[k] = wsum4[k*64+l] in VGPRs
// (64 VGPRs) -- the exact fragment the x-load index pattern needs.
__global__ void __launch_bounds__(256, 2)
matvec_kernel(const float* __restrict__ x, const float* __restrict__ wsum,
              float* __restrict__ out) {
    const int tid  = threadIdx.x;
    const int lane = tid & 63;
    const int gw   = blockIdx.x * 4 + (tid >> 6);         // wave id, 0..8191

    const f32x4* wv = reinterpret_cast<const f32x4*>(wsum);
    f32x4 w[16];
#pragma unroll
    for (int k = 0; k < 16; ++k)
        w[k] = wv[k * 64 + lane];

    const int row0 = gw * 4;                              // 4 rows per wave
#pragma unroll
    for (int r = 0; r < 4; ++r) {
        const int row = row0 + r;
        const f32x4* xv = reinterpret_cast<const f32x4*>(x) + (size_t)row * (INDIM / 4);
        float acc = 0.f;
#pragma unroll
        for (int k = 0; k < 16; ++k) {
            f32x4 xr = __builtin_nontemporal_load(&xv[k * 64 + lane]);
            acc += xr.x * w[k].x + xr.y * w[k].y + xr.z * w[k].z + xr.w * w[k].w;
        }
#pragma unroll
        for (int off = 32; off > 0; off >>= 1)
            acc += __shfl_down(acc, off, 64);
        if (lane == 0)
            out[row] = acc * 1.0f;   // COMBINED_SCALE = 2.0/2.0
    }
}

// ---------------------------------------------------------------------------
extern "C" void kernel_launch(void* const* d_in, const int* in_sizes, int n_in,
                              void* d_out, int out_size, void* d_ws, size_t ws_size,
                              hipStream_t stream) {
    const float* x = (const float*)d_in[0];        // (32768, 4096)
    const float* W = (const float*)d_in[1];        // (4096, 4096)
    float* out = (float*)d_out;                    // 32768 floats

    float* partial = (float*)d_ws;                               // 2 MiB
    float* wsum    = partial + (size_t)ROWCHUNKS * INDIM;        // 16 KiB

    colsum_partial_kernel<<<dim3(INDIM / 4 / 256, ROWCHUNKS), 256, 0, stream>>>(W, partial);
    colsum_final_kernel<<<dim3(INDIM / 256), 256, 0, stream>>>(partial, wsum);
    matvec_kernel<<<dim3(BATCH / 4 / 4), 256, 0, stream>>>(x, wsum, out);
}

// Round 4
// 106.255 us; speedup vs baseline: 1.0426x; 1.0426x over previous
//
#include <hip/hip_runtime.h>

// out[b] = sum_h (x @ W^T)[b,h] * 1.0  ==  dot(x[b,:], colsum_h(W))
// Phase 1: partial column sums of W.
// Phase 2: reduce 128 partials -> wsum (16 KiB).
// Phase 3: persistent matvec: 2048 blocks stage wsum in LDS once, then
//          grid-stride one-row-per-wave (32768 waves of work total).

#define BATCH   32768
#define HIDDEN  4096
#define INDIM   4096
#define ROWCHUNKS 128
#define ROWS_PER_CHUNK (HIDDEN / ROWCHUNKS)   // 32
#define MV_BLOCKS 2048                         // 8 blocks/CU
#define MV_WAVES  (MV_BLOCKS * 4)              // 8192 waves -> 4 rows each

typedef float f32x4 __attribute__((ext_vector_type(4)));

// ---------------------------------------------------------------------------
// Kernel 1: partial column sums. grid (4, 128), block 256 -> 512 blocks.
__global__ void __launch_bounds__(256)
colsum_partial_kernel(const float* __restrict__ W, float* __restrict__ partial) {
    const int col4 = blockIdx.x * 256 + threadIdx.x;      // 0..1023
    const int row0 = blockIdx.y * ROWS_PER_CHUNK;
    const f32x4* Wv = reinterpret_cast<const f32x4*>(W);
    f32x4 acc = {0.f, 0.f, 0.f, 0.f};
#pragma unroll 16
    for (int r = 0; r < ROWS_PER_CHUNK; ++r) {
        f32x4 v = __builtin_nontemporal_load(&Wv[(size_t)(row0 + r) * (INDIM / 4) + col4]);
        acc += v;
    }
    reinterpret_cast<f32x4*>(partial)[(size_t)blockIdx.y * (INDIM / 4) + col4] = acc;
}

// ---------------------------------------------------------------------------
// Kernel 2: reduce ROWCHUNKS partials -> wsum. One thread per column.
__global__ void __launch_bounds__(256)
colsum_final_kernel(const float* __restrict__ partial, float* __restrict__ wsum) {
    const int col = blockIdx.x * 256 + threadIdx.x;       // 0..4095
    float acc = 0.f;
#pragma unroll 8
    for (int p = 0; p < ROWCHUNKS; ++p)
        acc += partial[(size_t)p * INDIM + col];
    wsum[col] = acc;
}

// ---------------------------------------------------------------------------
// Kernel 3: persistent matvec. 2048 blocks x 256 threads; wsum staged in LDS
// once per block; each wave handles 4 rows spaced MV_WAVES apart (grid-stride)
// so every iteration keeps full 32-wave/CU parallelism and pure-stream loads.
__global__ void __launch_bounds__(256)
matvec_kernel(const float* __restrict__ x, const float* __restrict__ wsum,
              float* __restrict__ out) {
    __shared__ f32x4 wlds[INDIM / 4];                     // 16 KiB
    const int tid = threadIdx.x;
    const f32x4* wv = reinterpret_cast<const f32x4*>(wsum);
#pragma unroll
    for (int j = 0; j < 4; ++j)
        wlds[j * 256 + tid] = wv[j * 256 + tid];
    __syncthreads();

    const int lane = tid & 63;
    const int wid  = blockIdx.x * 4 + (tid >> 6);         // 0..MV_WAVES-1

    for (int iter = 0; iter < BATCH / MV_WAVES; ++iter) { // 4 iterations
        const int row = iter * MV_WAVES + wid;
        const f32x4* xv = reinterpret_cast<const f32x4*>(x) + (size_t)row * (INDIM / 4);
        float acc = 0.f;
#pragma unroll
        for (int k = 0; k < 16; ++k) {
            f32x4 xr = __builtin_nontemporal_load(&xv[k * 64 + lane]);
            f32x4 wr = wlds[k * 64 + lane];
            acc += xr.x * wr.x + xr.y * wr.y + xr.z * wr.z + xr.w * wr.w;
        }
#pragma unroll
        for (int off = 32; off > 0; off >>= 1)
            acc += __shfl_down(acc, off, 64);
        if (lane == 0)
            out[row] = acc * 1.0f;   // COMBINED_SCALE = 2.0/2.0
    }
}

// ---------------------------------------------------------------------------
extern "C" void kernel_launch(void* const* d_in, const int* in_sizes, int n_in,
                              void* d_out, int out_size, void* d_ws, size_t ws_size,
                              hipStream_t stream) {
    const float* x = (const float*)d_in[0];        // (32768, 4096)
    const float* W = (const float*)d_in[1];        // (4096, 4096)
    float* out = (float*)d_out;                    // 32768 floats

    float* partial = (float*)d_ws;                               // 2 MiB
    float* wsum    = partial + (size_t)ROWCHUNKS * INDIM;        // 16 KiB

    colsum_partial_kernel<<<dim3(INDIM / 4 / 256, ROWCHUNKS), 256, 0, stream>>>(W, partial);
    colsum_final_kernel<<<dim3(INDIM / 256), 256, 0, stream>>>(partial, wsum);
    matvec_kernel<<<dim3(MV_BLOCKS), 256, 0, stream>>>(x, wsum, out);
}

// Round 5
// 98.712 us; speedup vs baseline: 1.1223x; 1.0764x over previous
//
#include <hip/hip_runtime.h>

// out[b] = sum_h (x @ W^T)[b,h] * 1.0  ==  dot(x[b,:], colsum_h(W))
// Phase 1: partial column sums of W (R1-exact, 256 blocks).
// Phase 2: wide reduce of 64 partials -> wsum (64 blocks, ~2 us).
// Phase 3: matvec (R1-exact): 8192 blocks, LDS wsum, one row per wave.

#define BATCH   32768
#define HIDDEN  4096
#define INDIM   4096
#define ROWCHUNKS 64
#define ROWS_PER_CHUNK (HIDDEN / ROWCHUNKS)   // 64

typedef float f32x4 __attribute__((ext_vector_type(4)));

// ---------------------------------------------------------------------------
// Kernel 1: partial column sums. grid (4, 64), block 256 -> 256 blocks.
// Thread owns one float4 column-group, sums 64 rows.
__global__ void __launch_bounds__(256)
colsum_partial_kernel(const float* __restrict__ W, float* __restrict__ partial) {
    const int col4 = blockIdx.x * 256 + threadIdx.x;      // 0..1023
    const int row0 = blockIdx.y * ROWS_PER_CHUNK;
    const f32x4* Wv = reinterpret_cast<const f32x4*>(W);
    f32x4 acc = {0.f, 0.f, 0.f, 0.f};
#pragma unroll 16
    for (int r = 0; r < ROWS_PER_CHUNK; ++r) {
        f32x4 v = Wv[(size_t)(row0 + r) * (INDIM / 4) + col4];
        acc += v;
    }
    reinterpret_cast<f32x4*>(partial)[(size_t)blockIdx.y * (INDIM / 4) + col4] = acc;
}

// ---------------------------------------------------------------------------
// Kernel 2: wide reduce: 64 blocks x 256 threads, block owns 64 columns.
// Wave w sums chunks [w*16, w*16+16); lanes read 256 B contiguous per step.
// Cross-wave reduce via 1 KiB LDS. Fixed order -> deterministic.
__global__ void __launch_bounds__(256)
colsum_final_kernel(const float* __restrict__ partial, float* __restrict__ wsum) {
    __shared__ float red[4][64];
    const int t    = threadIdx.x;
    const int lane = t & 63;
    const int wave = t >> 6;
    const int col  = blockIdx.x * 64 + lane;
    float acc = 0.f;
#pragma unroll
    for (int p = 0; p < ROWCHUNKS / 4; ++p)               // 16 chunks per wave
        acc += partial[(size_t)(wave * (ROWCHUNKS / 4) + p) * INDIM + col];
    red[wave][lane] = acc;
    __syncthreads();
    if (wave == 0)
        wsum[col] = (red[0][lane] + red[1][lane]) + (red[2][lane] + red[3][lane]);
}

// ---------------------------------------------------------------------------
// Kernel 3 (R1-exact): out[b] = dot(x[b,:], wsum). One wave per row,
// 4 rows/block, 8192 blocks. wsum staged in LDS; hot loop issues only x loads.
__global__ void __launch_bounds__(256)
matvec_kernel(const float* __restrict__ x, const float* __restrict__ wsum,
              float* __restrict__ out) {
    __shared__ f32x4 wlds[INDIM / 4];                     // 16 KiB
    const int tid = threadIdx.x;
    const f32x4* wv = reinterpret_cast<const f32x4*>(wsum);
#pragma unroll
    for (int j = 0; j < 4; ++j)
        wlds[j * 256 + tid] = wv[j * 256 + tid];
    __syncthreads();

    const int row  = (blockIdx.x * 256 + tid) >> 6;       // global wave id
    const int lane = tid & 63;
    const f32x4* xv = reinterpret_cast<const f32x4*>(x) + (size_t)row * (INDIM / 4);

    float acc = 0.f;
#pragma unroll
    for (int k = 0; k < INDIM / 4 / 64; ++k) {            // 16 steps
        const int idx = k * 64 + lane;
        f32x4 xr = __builtin_nontemporal_load(&xv[idx]);
        f32x4 wr = wlds[idx];
        acc += xr.x * wr.x + xr.y * wr.y + xr.z * wr.z + xr.w * wr.w;
    }

#pragma unroll
    for (int off = 32; off > 0; off >>= 1)
        acc += __shfl_down(acc, off, 64);

    if (lane == 0)
        out[row] = acc * 1.0f;   // COMBINED_SCALE = 2.0/2.0
}

// ---------------------------------------------------------------------------
extern "C" void kernel_launch(void* const* d_in, const int* in_sizes, int n_in,
                              void* d_out, int out_size, void* d_ws, size_t ws_size,
                              hipStream_t stream) {
    const float* x = (const float*)d_in[0];        // (32768, 4096)
    const float* W = (const float*)d_in[1];        // (4096, 4096)
    float* out = (float*)d_out;                    // 32768 floats

    float* partial = (float*)d_ws;                               // 1 MiB
    float* wsum    = partial + (size_t)ROWCHUNKS * INDIM;        // 16 KiB

    colsum_partial_kernel<<<dim3(INDIM / 4 / 256, ROWCHUNKS), 256, 0, stream>>>(W, partial);
    colsum_final_kernel<<<dim3(INDIM / 64), 256, 0, stream>>>(partial, wsum);
    matvec_kernel<<<dim3(BATCH / 4), 256, 0, stream>>>(x, wsum, out);
}